// Round 1
// baseline (435.057 us; speedup 1.0000x reference)
//
#include <hip/hip_runtime.h>
#include <math.h>

#define BATCH   4096
#define TSTEPS  512
#define FDIM    32
#define UNITS   8
#define G4      32      // 4*U
#define CH      8       // timesteps staged per LDS chunk
#define RPB     8       // rows per block (4 waves * 2 rows/wave)

// ds_swizzle with compile-time pattern (BitMode: offset = (xor<<10)|(or<<5)|and)
template<int PAT>
__device__ __forceinline__ float swzf(float v) {
    return __int_as_float(__builtin_amdgcn_ds_swizzle(__float_as_int(v), PAT));
}

__device__ __forceinline__ float fast_rcp(float x) { return __builtin_amdgcn_rcpf(x); }

__device__ __forceinline__ float fast_tanh(float x) {
    // tanh(x) = 1 - 2/(e^{2x}+1); e->inf => 1, e->0 => -1 (both correct)
    float e = __expf(2.0f * x);
    return 1.0f - 2.0f * fast_rcp(e + 1.0f);
}

__device__ __forceinline__ float sigmoidf_(float x) {
    return fast_rcp(1.0f + __expf(-x));
}

__global__ __launch_bounds__(256, 2)
void lstm_fused(const float* __restrict__ x,
                const float* __restrict__ kern,
                const float* __restrict__ rk,
                const float* __restrict__ bias,
                const float* __restrict__ w1,
                const float* __restrict__ b1,
                const float* __restrict__ w2,
                const float* __restrict__ b2,
                float* __restrict__ out)
{
    const int tid  = threadIdx.x;
    const int wv   = tid >> 6;          // wave id in block (0..3)
    const int half = (tid >> 5) & 1;    // which row of the wave's pair
    const int j    = tid & 31;          // gate-output column 0..31
    const int row  = blockIdx.x * RPB + wv * 2 + half;

    // [slot][wave][half][CH*FDIM] : per-wave private staging, wave-synchronous (no barriers)
    __shared__ __align__(16) float sx[2][4][2][CH * FDIM];

    // --- weights resident in registers (per-lane column j) ---
    float Kc[FDIM];
#pragma unroll
    for (int f = 0; f < FDIM; ++f) Kc[f] = kern[f * G4 + j];
    float Rc[UNITS];
#pragma unroll
    for (int u = 0; u < UNITS; ++u) Rc[u] = rk[u * G4 + j];
    const float bj  = bias[j];
    const bool  isg = ((j >> 3) == 2);  // lanes 16..23 compute the tanh 'g' gate

    const float* xrow = x + (size_t)row * (TSTEPS * FDIM);

    // LSTM state: c for unit (j&7), replicated x4; h[0..7] replicated in all lanes
    float h0=0.f,h1=0.f,h2=0.f,h3=0.f,h4=0.f,h5=0.f,h6=0.f,h7=0.f, c=0.f;

    // --- prologue: stage chunk 0, prefetch chunk 1 into regs ---
    float4 pa, pb;
    {
        const float4* p = (const float4*)xrow;            // chunk 0: floats [0, 256)
        float4 a = p[j], b = p[j + 32];
        float4* q = (float4*)&sx[0][wv][half][0];
        q[j] = a; q[j + 32] = b;
        const float4* p1 = (const float4*)(xrow + CH * FDIM);
        pa = p1[j]; pb = p1[j + 32];
    }

    int slot = 0;
    for (int tc = 0; tc < TSTEPS; tc += CH) {
        const float* xt0 = &sx[slot][wv][half][0];
#pragma unroll
        for (int k = 0; k < CH; ++k) {
            const float4* xv4 = (const float4*)(xt0 + k * FDIM);
            // z_j = bias_j + x_t . K[:,j]  (4 accumulators to break the dep chain)
            float z0 = bj, z1 = 0.f, z2 = 0.f, z3 = 0.f;
#pragma unroll
            for (int f0 = 0; f0 < 8; ++f0) {
                float4 xv = xv4[f0];                       // broadcast ds_read_b128
                z0 = fmaf(xv.x, Kc[4 * f0 + 0], z0);
                z1 = fmaf(xv.y, Kc[4 * f0 + 1], z1);
                z2 = fmaf(xv.z, Kc[4 * f0 + 2], z2);
                z3 = fmaf(xv.w, Kc[4 * f0 + 3], z3);
            }
            // + h . R[:,j]
            z0 = fmaf(h0, Rc[0], z0); z1 = fmaf(h1, Rc[1], z1);
            z2 = fmaf(h2, Rc[2], z2); z3 = fmaf(h3, Rc[3], z3);
            z0 = fmaf(h4, Rc[4], z0); z1 = fmaf(h5, Rc[5], z1);
            z2 = fmaf(h6, Rc[6], z2); z3 = fmaf(h7, Rc[7], z3);
            float z = (z0 + z1) + (z2 + z3);

            // activation: relu for i/f/o lanes, tanh for g lanes
            float a = isg ? fast_tanh(z) : fmaxf(z, 0.f);

            // gather the 4 gate values for unit u=(j&7): src lanes u, u+8, u+16, u+24
            float ai = swzf<0x007>(a);
            float af = swzf<0x107>(a);
            float ag = swzf<0x207>(a);
            float ao = swzf<0x307>(a);

            c = fmaf(af, c, ai * ag);
            float hn = ao * fast_tanh(c);

            // broadcast h[u'] from lane (l&0x18)|u' (nearest replica group)
            h0 = swzf<0x018>(hn); h1 = swzf<0x038>(hn);
            h2 = swzf<0x058>(hn); h3 = swzf<0x078>(hn);
            h4 = swzf<0x098>(hn); h5 = swzf<0x0B8>(hn);
            h6 = swzf<0x0D8>(hn); h7 = swzf<0x0F8>(hn);
        }
        // stage next chunk (prefetched regs -> other slot), prefetch chunk+2
        if (tc + CH < TSTEPS) {
            float4* q = (float4*)&sx[slot ^ 1][wv][half][0];
            q[j] = pa; q[j + 32] = pb;
            if (tc + 2 * CH < TSTEPS) {
                const float4* p = (const float4*)(xrow + (tc + 2 * CH) * FDIM);
                pa = p[j]; pb = p[j + 32];
            }
            slot ^= 1;
        }
    }

    // --- MLP head: m = relu(h @ w1 + b1) [64], out = sigmoid(m @ w2 + b2) [4] ---
    const float hh[8] = {h0, h1, h2, h3, h4, h5, h6, h7};
    float m0 = b1[j], m1 = b1[j + 32];
#pragma unroll
    for (int u = 0; u < 8; ++u) {
        m0 = fmaf(hh[u], w1[u * 64 + j],      m0);
        m1 = fmaf(hh[u], w1[u * 64 + 32 + j], m1);
    }
    m0 = fmaxf(m0, 0.f);
    m1 = fmaxf(m1, 0.f);

    float p0 = m0 * w2[j * 4 + 0] + m1 * w2[(j + 32) * 4 + 0];
    float p1 = m0 * w2[j * 4 + 1] + m1 * w2[(j + 32) * 4 + 1];
    float p2 = m0 * w2[j * 4 + 2] + m1 * w2[(j + 32) * 4 + 2];
    float p3 = m0 * w2[j * 4 + 3] + m1 * w2[(j + 32) * 4 + 3];

    // butterfly reduce across the 32-lane row group
    p0 += swzf<0x041F>(p0); p1 += swzf<0x041F>(p1); p2 += swzf<0x041F>(p2); p3 += swzf<0x041F>(p3);
    p0 += swzf<0x081F>(p0); p1 += swzf<0x081F>(p1); p2 += swzf<0x081F>(p2); p3 += swzf<0x081F>(p3);
    p0 += swzf<0x101F>(p0); p1 += swzf<0x101F>(p1); p2 += swzf<0x101F>(p2); p3 += swzf<0x101F>(p3);
    p0 += swzf<0x201F>(p0); p1 += swzf<0x201F>(p1); p2 += swzf<0x201F>(p2); p3 += swzf<0x201F>(p3);
    p0 += swzf<0x401F>(p0); p1 += swzf<0x401F>(p1); p2 += swzf<0x401F>(p2); p3 += swzf<0x401F>(p3);

    if (j == 0) {
        float4 o;
        o.x = sigmoidf_(p0 + b2[0]);
        o.y = sigmoidf_(p1 + b2[1]);
        o.z = sigmoidf_(p2 + b2[2]);
        o.w = sigmoidf_(p3 + b2[3]);
        *(float4*)&out[row * 4] = o;
    }
}

extern "C" void kernel_launch(void* const* d_in, const int* in_sizes, int n_in,
                              void* d_out, int out_size, void* d_ws, size_t ws_size,
                              hipStream_t stream)
{
    const float* x    = (const float*)d_in[0];
    const float* kern = (const float*)d_in[1];
    const float* rk   = (const float*)d_in[2];
    const float* bias = (const float*)d_in[3];
    const float* w1   = (const float*)d_in[4];
    const float* b1   = (const float*)d_in[5];
    const float* w2   = (const float*)d_in[6];
    const float* b2   = (const float*)d_in[7];

    dim3 grid(BATCH / RPB);   // 512 blocks
    dim3 block(256);
    lstm_fused<<<grid, block, 0, stream>>>(x, kern, rk, bias, w1, b1, w2, b2, (float*)d_out);
}